// Round 1
// baseline (2155.120 us; speedup 1.0000x reference)
//
#include <hip/hip_runtime.h>
#include <stdint.h>
#include <math.h>

// ---------------------------------------------------------------------------
// BitAttention: B=2, T=2048, D=2048, H=16, HD=128
//   q/k/v = int4-quant(x) @ ternary(w)^T   (exact integer math via bf16 MFMA)
//   rope(q), rope(k); softmax(q k^T / sqrt(128)) @ v  (f32 flash attention)
//   out = int8-quant(topk_0.55(attn)) @ ternary(wo)^T (exact int via MFMA)
// ---------------------------------------------------------------------------

typedef __attribute__((ext_vector_type(8))) short short8;
typedef __attribute__((ext_vector_type(4))) float f32x4;

#define GLDS16(g, l)                                                        \
  __builtin_amdgcn_global_load_lds(                                         \
      (const __attribute__((address_space(1))) void*)(g),                   \
      (__attribute__((address_space(3))) void*)(l), 16, 0, 0)

__device__ __forceinline__ unsigned short f2bf(float v) {
  // exact for the small-integer values we store
  return (unsigned short)(__float_as_uint(v) >> 16);
}

// ---------------- cos/sin tables (T x 64), faithful f32 path ---------------
__global__ __launch_bounds__(256) void k_costab(float* __restrict__ ct,
                                                float* __restrict__ st) {
  int idx = blockIdx.x * 256 + threadIdx.x;  // 2048*64
  int t = idx >> 6, i = idx & 63;
  float f = (float)(2 * i) / 128.0f;
  float inv = 1.0f / powf(10000.0f, f);
  float fr = (float)t * inv;
  ct[idx] = cosf(fr);
  st[idx] = sinf(fr);
}

// ---------------- weight scale: mean(|w|), deterministic f64 tree ----------
__global__ __launch_bounds__(256) void k_wsum(const float* __restrict__ w0,
                                              const float* __restrict__ w1,
                                              const float* __restrict__ w2,
                                              const float* __restrict__ w3,
                                              double* __restrict__ part) {
  int bx = blockIdx.x;  // 0..4095 ; 1024 blocks per matrix
  int mat = bx >> 10;
  const float* w = (mat == 0) ? w0 : (mat == 1) ? w1 : (mat == 2) ? w2 : w3;
  int base = (bx & 1023) * 4096;
  double s = 0.0;
#pragma unroll
  for (int i = 0; i < 16; ++i)
    s += (double)fabsf(w[base + threadIdx.x + i * 256]);
  __shared__ double red[256];
  red[threadIdx.x] = s;
  __syncthreads();
  for (int off = 128; off; off >>= 1) {
    if (threadIdx.x < off) red[threadIdx.x] += red[threadIdx.x + off];
    __syncthreads();
  }
  if (threadIdx.x == 0) part[bx] = red[0];
}

__global__ __launch_bounds__(256) void k_wscale(const double* __restrict__ part,
                                                float* __restrict__ wsc) {
  int m = blockIdx.x, tid = threadIdx.x;
  const double* p = part + m * 1024;
  double s = p[tid] + p[tid + 256] + p[tid + 512] + p[tid + 768];
  __shared__ double red[256];
  red[tid] = s;
  __syncthreads();
  for (int off = 128; off; off >>= 1) {
    if (tid < off) red[tid] += red[tid + off];
    __syncthreads();
  }
  if (tid == 0) wsc[m] = (float)(red[0] / 4194304.0);
}

// ---------------- ternary quantize weights -> bf16 {-1,0,1} ----------------
__global__ __launch_bounds__(256) void k_wquant(const float* __restrict__ w0,
                                                const float* __restrict__ w1,
                                                const float* __restrict__ w2,
                                                const float* __restrict__ w3,
                                                const float* __restrict__ wsc,
                                                unsigned short* __restrict__ wt) {
  int mat = blockIdx.y;
  const float* w = (mat == 0) ? w0 : (mat == 1) ? w1 : (mat == 2) ? w2 : w3;
  float se = wsc[mat] + 1e-5f;
  size_t base = (size_t)blockIdx.x * 4096;
  unsigned short* o = wt + (size_t)mat * 4194304 + base;
  const float* wp = w + base;
#pragma unroll 4
  for (int i = 0; i < 16; ++i) {
    int idx = threadIdx.x + i * 256;
    float v = rintf(wp[idx] / se);
    v = fminf(fmaxf(v, -1.0f), 1.0f);
    o[idx] = f2bf(v);
  }
}

// ---------------- int4 row-quantize x -> bf16 ints + 1/s scale -------------
__global__ __launch_bounds__(256) void k_xquant(const float* __restrict__ x,
                                                unsigned short* __restrict__ xq,
                                                float* __restrict__ sx) {
  int row = blockIdx.x, tid = threadIdx.x;
  const float* xr = x + (size_t)row * 2048;
  float v[8];
  float mx = 0.0f;
#pragma unroll
  for (int i = 0; i < 8; ++i) {
    v[i] = xr[tid + i * 256];
    mx = fmaxf(mx, fabsf(v[i]));
  }
  __shared__ float red[256];
  red[tid] = mx;
  __syncthreads();
  for (int off = 128; off; off >>= 1) {
    if (tid < off) red[tid] = fmaxf(red[tid], red[tid + off]);
    __syncthreads();
  }
  float s = 7.0f / fmaxf(red[0], 1e-5f);
#pragma unroll
  for (int i = 0; i < 8; ++i) {
    float q = rintf(v[i] * s);
    q = fminf(fmaxf(q, -8.0f), 7.0f);
    xq[(size_t)row * 2048 + tid + i * 256] = f2bf(q);
  }
  if (tid == 0) sx[row] = s;
}

// ---------------- GEMM: C[i,j] = (sum xq[i,:]*wt[j,:]) * wscale / s_i ------
// 128x128 tile, BK=32, 4 waves, global_load_lds, bf16 MFMA (exact int math)
__global__ __launch_bounds__(256) void k_gemm(const unsigned short* __restrict__ A,
                                              const unsigned short* __restrict__ Bw,
                                              float* __restrict__ C,
                                              const float* __restrict__ srow,
                                              const float* __restrict__ wsp) {
  __shared__ unsigned short As[128 * 32];
  __shared__ unsigned short Bs[128 * 32];
  __shared__ float fac[128];
  const int tid = threadIdx.x, wave = tid >> 6, lane = tid & 63;
  const int brow = blockIdx.y * 128, bcol = blockIdx.x * 128;
  if (tid < 128) fac[tid] = wsp[0] / srow[brow + tid];
  const int wr = wave >> 1, wc = wave & 1;
  f32x4 acc[4][4];
#pragma unroll
  for (int m = 0; m < 4; ++m)
#pragma unroll
    for (int n = 0; n < 4; ++n) acc[m][n] = (f32x4){0.f, 0.f, 0.f, 0.f};
  const int srl = (wave << 4) + (lane >> 2);  // staged row 0..63
  const int scl = (lane & 3) * 8;             // staged k offset
  const unsigned short* Ag = A + (size_t)(brow + srl) * 2048 + scl;
  const unsigned short* Bg = Bw + (size_t)(bcol + srl) * 2048 + scl;
  char* AsB = (char*)As + wave * 1024;
  char* BsB = (char*)Bs + wave * 1024;
  const int fr = lane & 15, fk = (lane >> 4) << 3;
  for (int k0 = 0; k0 < 2048; k0 += 32) {
    __syncthreads();  // previous MFMA reads done
    GLDS16(Ag + k0, AsB);
    GLDS16(Ag + k0 + (size_t)64 * 2048, AsB + 4096);
    GLDS16(Bg + k0, BsB);
    GLDS16(Bg + k0 + (size_t)64 * 2048, BsB + 4096);
    __syncthreads();  // loads visible
    short8 af[4], bf[4];
#pragma unroll
    for (int m = 0; m < 4; ++m)
      af[m] = *(const short8*)&As[(wr * 64 + m * 16 + fr) * 32 + fk];
#pragma unroll
    for (int n = 0; n < 4; ++n)
      bf[n] = *(const short8*)&Bs[(wc * 64 + n * 16 + fr) * 32 + fk];
#pragma unroll
    for (int m = 0; m < 4; ++m)
#pragma unroll
      for (int n = 0; n < 4; ++n)
        acc[m][n] = __builtin_amdgcn_mfma_f32_16x16x32_bf16(af[m], bf[n],
                                                            acc[m][n], 0, 0, 0);
  }
  const int fq = lane >> 4;
#pragma unroll
  for (int m = 0; m < 4; ++m)
#pragma unroll
    for (int n = 0; n < 4; ++n)
#pragma unroll
      for (int r = 0; r < 4; ++r) {
        int row = wr * 64 + m * 16 + fq * 4 + r;
        C[(size_t)(brow + row) * 2048 + bcol + wc * 64 + n * 16 + fr] =
            acc[m][n][r] * fac[row];
      }
}

// ---------------- RoPE in-place on (B,T,D) q/k buffers ---------------------
__global__ __launch_bounds__(256) void k_rope(float* __restrict__ qb,
                                              float* __restrict__ kb,
                                              const float* __restrict__ ct,
                                              const float* __restrict__ st) {
  int idx = blockIdx.x * 256 + threadIdx.x;  // 4,194,304 pairs
  float* buf = blockIdx.y ? kb : qb;
  int hd = idx & 63;
  int h = (idx >> 6) & 15;
  int row = idx >> 10;  // 0..4095
  int t = row & 2047;
  size_t base = (size_t)row * 2048 + h * 128 + hd;
  float c = ct[t * 64 + hd], s = st[t * 64 + hd];
  float x1 = buf[base], x2 = buf[base + 64];
  buf[base] = x1 * c - x2 * s;
  buf[base + 64] = x2 * c + x1 * s;
}

// ---------------- flash attention, f32, QT=KT=32, out in-place to qb -------
__global__ __launch_bounds__(256) void k_attn(float* __restrict__ qb,
                                              const float* __restrict__ kb,
                                              const float* __restrict__ vg) {
  __shared__ float Qs[128][36];   // [d][r] transposed
  __shared__ float KV[128 * 36];  // K view [d][c]*36 ; V view [k][c]*132
  __shared__ float Ps[32 * 33];   // [k][r]
  __shared__ float red[256];
  __shared__ float mbuf[32], lbuf[32], abuf[32];
  const int tid = threadIdx.x;
  const int qt = blockIdx.x, bh = blockIdx.y;
  const int b = bh >> 4, h = bh & 15;
  const size_t rowbase = (size_t)b * 2048;
  const float SCALE = 0.08838834764831845f;  // 1/sqrt(128)
  {  // stage Q transposed
    const int c = tid >> 3, ds = (tid & 7) * 16;
    const float* src = qb + (rowbase + qt * 32 + c) * 2048 + h * 128 + ds;
#pragma unroll
    for (int j = 0; j < 4; ++j) {
      float4 v = *(const float4*)(src + j * 4);
      Qs[ds + j * 4 + 0][c] = v.x;
      Qs[ds + j * 4 + 1][c] = v.y;
      Qs[ds + j * 4 + 2][c] = v.z;
      Qs[ds + j * 4 + 3][c] = v.w;
    }
  }
  if (tid < 32) { mbuf[tid] = -INFINITY; lbuf[tid] = 0.0f; }
  float accO[2][8] = {};
  const int rb = tid >> 4, cb = tid & 15;
  const int part = tid >> 5, rr = tid & 31;
  for (int kt = 0; kt < 64; ++kt) {
    __syncthreads();  // prev PV done / Q staged
    {                 // stage K transposed
      const int c = tid >> 3, ds = (tid & 7) * 16;
      const float* src = kb + (rowbase + kt * 32 + c) * 2048 + h * 128 + ds;
#pragma unroll
      for (int j = 0; j < 4; ++j) {
        float4 v = *(const float4*)(src + j * 4);
        KV[(ds + j * 4 + 0) * 36 + c] = v.x;
        KV[(ds + j * 4 + 1) * 36 + c] = v.y;
        KV[(ds + j * 4 + 2) * 36 + c] = v.z;
        KV[(ds + j * 4 + 3) * 36 + c] = v.w;
      }
    }
    __syncthreads();
    // QK^T : 2x2 per thread
    float s00 = 0.f, s01 = 0.f, s10 = 0.f, s11 = 0.f;
#pragma unroll 4
    for (int d = 0; d < 128; ++d) {
      float2 q2 = *(const float2*)&Qs[d][rb * 2];
      float2 k2 = *(const float2*)&KV[d * 36 + cb * 2];
      s00 += q2.x * k2.x;
      s01 += q2.x * k2.y;
      s10 += q2.y * k2.x;
      s11 += q2.y * k2.y;
    }
    Ps[(cb * 2 + 0) * 33 + rb * 2 + 0] = s00;
    Ps[(cb * 2 + 1) * 33 + rb * 2 + 0] = s01;
    Ps[(cb * 2 + 0) * 33 + rb * 2 + 1] = s10;
    Ps[(cb * 2 + 1) * 33 + rb * 2 + 1] = s11;
    __syncthreads();
    // tile row-max partials
    float pm = -INFINITY;
#pragma unroll
    for (int i = 0; i < 4; ++i) pm = fmaxf(pm, Ps[(part * 4 + i) * 33 + rr]);
    red[part * 32 + rr] = pm;
    __syncthreads();
    if (tid < 32) {
      float tm = red[tid];
#pragma unroll
      for (int p = 1; p < 8; ++p) tm = fmaxf(tm, red[p * 32 + tid]);
      tm *= SCALE;
      float mo = mbuf[tid];
      float mn = fmaxf(mo, tm);
      abuf[tid] = expf(mo - mn);
      mbuf[tid] = mn;
    }
    __syncthreads();
    {  // P = exp(scaled - m_new), partial sums
      float mn = mbuf[rr];
      float ps = 0.0f;
#pragma unroll
      for (int i = 0; i < 4; ++i) {
        float e = expf(Ps[(part * 4 + i) * 33 + rr] * SCALE - mn);
        Ps[(part * 4 + i) * 33 + rr] = e;
        ps += e;
      }
      red[part * 32 + rr] = ps;
    }
    {  // stage V (reuses KV; K reads finished)
      const int vr = tid & 31, seg = tid >> 5;
      const float* src = vg + (rowbase + kt * 32 + vr) * 2048 + h * 128 + seg * 16;
#pragma unroll
      for (int j = 0; j < 4; ++j)
        *(float4*)&KV[vr * 132 + seg * 16 + j * 4] = *(const float4*)(src + j * 4);
    }
    {  // rescale running O
      float a0 = abuf[rb * 2 + 0], a1 = abuf[rb * 2 + 1];
#pragma unroll
      for (int j = 0; j < 8; ++j) {
        accO[0][j] *= a0;
        accO[1][j] *= a1;
      }
    }
    __syncthreads();
    if (tid < 32) {
      float s8 = red[tid];
#pragma unroll
      for (int p = 1; p < 8; ++p) s8 += red[p * 32 + tid];
      lbuf[tid] = abuf[tid] * lbuf[tid] + s8;
    }
    // PV accumulate
#pragma unroll 2
    for (int k = 0; k < 32; ++k) {
      float p0 = Ps[k * 33 + rb * 2 + 0];
      float p1 = Ps[k * 33 + rb * 2 + 1];
      float4 va = *(const float4*)&KV[k * 132 + cb * 8];
      float4 vb4 = *(const float4*)&KV[k * 132 + cb * 8 + 4];
      accO[0][0] += p0 * va.x;  accO[0][1] += p0 * va.y;
      accO[0][2] += p0 * va.z;  accO[0][3] += p0 * va.w;
      accO[0][4] += p0 * vb4.x; accO[0][5] += p0 * vb4.y;
      accO[0][6] += p0 * vb4.z; accO[0][7] += p0 * vb4.w;
      accO[1][0] += p1 * va.x;  accO[1][1] += p1 * va.y;
      accO[1][2] += p1 * va.z;  accO[1][3] += p1 * va.w;
      accO[1][4] += p1 * vb4.x; accO[1][5] += p1 * vb4.y;
      accO[1][6] += p1 * vb4.z; accO[1][7] += p1 * vb4.w;
    }
  }
  __syncthreads();
  {
    float li0 = 1.0f / lbuf[rb * 2 + 0];
    float li1 = 1.0f / lbuf[rb * 2 + 1];
    float* d0 = qb + (rowbase + qt * 32 + rb * 2 + 0) * 2048 + h * 128 + cb * 8;
    float* d1 = d0 + 2048;
    float4 o;
    o.x = accO[0][0] * li0; o.y = accO[0][1] * li0;
    o.z = accO[0][2] * li0; o.w = accO[0][3] * li0;
    *(float4*)d0 = o;
    o.x = accO[0][4] * li0; o.y = accO[0][5] * li0;
    o.z = accO[0][6] * li0; o.w = accO[0][7] * li0;
    *(float4*)(d0 + 4) = o;
    o.x = accO[1][0] * li1; o.y = accO[1][1] * li1;
    o.z = accO[1][2] * li1; o.w = accO[1][3] * li1;
    *(float4*)d1 = o;
    o.x = accO[1][4] * li1; o.y = accO[1][5] * li1;
    o.z = accO[1][6] * li1; o.w = accO[1][7] * li1;
    *(float4*)(d1 + 4) = o;
  }
}

// ---------------- topk(0.55)+int8 quantize per row (exact tie handling) ----
__global__ __launch_bounds__(256) void k_topk(const float* __restrict__ ain,
                                              unsigned short* __restrict__ oq,
                                              float* __restrict__ so) {
  const int row = blockIdx.x, tid = threadIdx.x;
  const float* xr = ain + (size_t)row * 2048;
  __shared__ unsigned int bits[2048];
  __shared__ unsigned int hist[256];
  __shared__ unsigned int scn[256];
  __shared__ unsigned int stat[3];  // prefix, rk, maxbits
#pragma unroll
  for (int j = 0; j < 8; ++j) {
    int i = tid * 8 + j;
    bits[i] = __float_as_uint(xr[i]) & 0x7fffffffu;
  }
  unsigned int mx = 0;
#pragma unroll
  for (int j = 0; j < 8; ++j) mx = max(mx, bits[tid * 8 + j]);
  scn[tid] = mx;
  __syncthreads();
  for (int off = 128; off; off >>= 1) {
    if (tid < off) scn[tid] = max(scn[tid], scn[tid + off]);
    __syncthreads();
  }
  if (tid == 0) { stat[0] = 0u; stat[1] = 1126u; stat[2] = scn[0]; }
  // 4-pass radix select (exact 32-bit threshold)
  for (int p = 0; p < 4; ++p) {
    const int shift = 24 - 8 * p;
    hist[tid] = 0u;
    __syncthreads();
    unsigned int pref = stat[0];
    unsigned int rk0 = stat[1];
#pragma unroll
    for (int j = 0; j < 8; ++j) {
      unsigned int u = bits[tid * 8 + j];
      bool match = (p == 0) || ((u >> (shift + 8)) == pref);
      if (match) atomicAdd(&hist[(u >> shift) & 255u], 1u);
    }
    __syncthreads();
    // suffix sums: scn[b] = sum_{bb>=b} hist[bb]
    scn[tid] = hist[tid];
    __syncthreads();
    for (int off = 1; off < 256; off <<= 1) {
      unsigned int v = (tid + off < 256) ? scn[tid + off] : 0u;
      __syncthreads();
      scn[tid] += v;
      __syncthreads();
    }
    unsigned int nxt = (tid == 255) ? 0u : scn[tid + 1];
    if (scn[tid] >= rk0 && nxt < rk0) {
      stat[0] = (pref << 8) | (unsigned int)tid;
      stat[1] = rk0 - nxt;
    }
    __syncthreads();
  }
  const unsigned int T = stat[0];
  const unsigned int rkeep = stat[1];
  const float rowmax = __uint_as_float(stat[2]);
  const float s = 127.0f / fmaxf(rowmax, 1e-5f);
  // rank-among-equals (index order), exclusive prefix over contiguous chunks
  unsigned int cnt = 0;
#pragma unroll
  for (int j = 0; j < 8; ++j) cnt += (bits[tid * 8 + j] == T) ? 1u : 0u;
  scn[tid] = cnt;
  __syncthreads();
  for (int off = 1; off < 256; off <<= 1) {
    unsigned int v = (tid >= off) ? scn[tid - off] : 0u;
    __syncthreads();
    scn[tid] += v;
    __syncthreads();
  }
  unsigned int eqr = scn[tid] - cnt;
#pragma unroll
  for (int j = 0; j < 8; ++j) {
    int i = tid * 8 + j;
    unsigned int u = bits[i];
    bool keep = u > T;
    if (u == T) { keep = (eqr < rkeep); eqr++; }
    float q = 0.0f;
    if (keep) {
      q = rintf(xr[i] * s);
      q = fminf(fmaxf(q, -128.0f), 127.0f);
    }
    oq[(size_t)row * 2048 + i] = f2bf(q);
  }
  if (tid == 0) so[row] = s;
}

// ---------------------------------------------------------------------------
extern "C" void kernel_launch(void* const* d_in, const int* in_sizes, int n_in,
                              void* d_out, int out_size, void* d_ws,
                              size_t ws_size, hipStream_t stream) {
  const float* x = (const float*)d_in[0];
  const float* wq = (const float*)d_in[1];
  const float* wk = (const float*)d_in[2];
  const float* wv = (const float*)d_in[3];
  const float* wo = (const float*)d_in[4];
  float* out = (float*)d_out;

  char* ws = (char*)d_ws;
  size_t off = 0;
  auto alloc = [&](size_t bytes) -> void* {
    void* p = ws + off;
    off += (bytes + 255) & ~(size_t)255;
    return p;
  };
  unsigned short* wt = (unsigned short*)alloc(4ull * 2048 * 2048 * 2);  // 33.5MB
  unsigned short* xq = (unsigned short*)alloc(4096ull * 2048 * 2);      // 16.8MB
  float* qb = (float*)alloc(4096ull * 2048 * 4);                        // 33.5MB
  float* kb = (float*)alloc(4096ull * 2048 * 4);
  float* vb = (float*)alloc(4096ull * 2048 * 4);
  float* ct = (float*)alloc(2048ull * 64 * 4);
  float* st = (float*)alloc(2048ull * 64 * 4);
  float* sx = (float*)alloc(4096 * 4);
  float* so = (float*)alloc(4096 * 4);
  float* wsc = (float*)alloc(4 * 4);
  double* prt = (double*)alloc(4096 * 8);
  unsigned short* oq = (unsigned short*)vb;  // overlay: vb dead after attention

  k_costab<<<512, 256, 0, stream>>>(ct, st);
  k_wsum<<<4096, 256, 0, stream>>>(wq, wk, wv, wo, prt);
  k_wscale<<<4, 256, 0, stream>>>(prt, wsc);
  k_wquant<<<dim3(1024, 4), 256, 0, stream>>>(wq, wk, wv, wo, wsc, wt);
  k_xquant<<<4096, 256, 0, stream>>>(x, xq, sx);

  dim3 gg(16, 32);
  k_gemm<<<gg, 256, 0, stream>>>(xq, wt + 0ull * 4194304, qb, sx, wsc + 0);
  k_gemm<<<gg, 256, 0, stream>>>(xq, wt + 1ull * 4194304, kb, sx, wsc + 1);
  k_gemm<<<gg, 256, 0, stream>>>(xq, wt + 2ull * 4194304, vb, sx, wsc + 2);

  k_rope<<<dim3(16384, 2), 256, 0, stream>>>(qb, kb, ct, st);
  k_attn<<<dim3(64, 32), 256, 0, stream>>>(qb, kb, vb);  // out -> qb in-place
  k_topk<<<4096, 256, 0, stream>>>(qb, oq, so);
  k_gemm<<<gg, 256, 0, stream>>>(oq, wt + 3ull * 4194304, out, so, wsc + 3);
}

// Round 2
// 588.030 us; speedup vs baseline: 3.6650x; 3.6650x over previous
//
#include <hip/hip_runtime.h>
#include <stdint.h>
#include <math.h>

// ---------------------------------------------------------------------------
// BitAttention: B=2, T=2048, D=2048, H=16, HD=128
//   q/k/v = int4-quant(x) @ ternary(w)^T   (exact integer math via bf16 MFMA)
//   rope(q), rope(k); MFMA flash attention (f16 hi/lo split ~ f32 accurate)
//   out = int8-quant(topk_0.55(attn)) @ ternary(wo)^T (exact int via MFMA)
// ---------------------------------------------------------------------------

typedef __attribute__((ext_vector_type(8))) short short8;
typedef __attribute__((ext_vector_type(4))) float f32x4;
typedef __attribute__((ext_vector_type(8))) _Float16 f16x8;
typedef __attribute__((ext_vector_type(16))) float f32x16;

#define GLDS16(g, l)                                                        \
  __builtin_amdgcn_global_load_lds(                                         \
      (const __attribute__((address_space(1))) void*)(g),                   \
      (__attribute__((address_space(3))) void*)(l), 16, 0, 0)

__device__ __forceinline__ unsigned short f2bf(float v) {
  // exact for the small-integer values we store
  return (unsigned short)(__float_as_uint(v) >> 16);
}

__device__ __forceinline__ unsigned int pk2(_Float16 a, _Float16 b) {
  return (unsigned int)__builtin_bit_cast(unsigned short, a) |
         ((unsigned int)__builtin_bit_cast(unsigned short, b) << 16);
}

// ---------------- cos/sin tables (T x 64), faithful f32 path ---------------
__global__ __launch_bounds__(256) void k_costab(float* __restrict__ ct,
                                                float* __restrict__ st) {
  int idx = blockIdx.x * 256 + threadIdx.x;  // 2048*64
  int t = idx >> 6, i = idx & 63;
  float f = (float)(2 * i) / 128.0f;
  float inv = 1.0f / powf(10000.0f, f);
  float fr = (float)t * inv;
  ct[idx] = cosf(fr);
  st[idx] = sinf(fr);
}

// ---------------- weight scale: mean(|w|), deterministic f64 tree ----------
__global__ __launch_bounds__(256) void k_wsum(const float* __restrict__ w0,
                                              const float* __restrict__ w1,
                                              const float* __restrict__ w2,
                                              const float* __restrict__ w3,
                                              double* __restrict__ part) {
  int bx = blockIdx.x;  // 0..4095 ; 1024 blocks per matrix
  int mat = bx >> 10;
  const float* w = (mat == 0) ? w0 : (mat == 1) ? w1 : (mat == 2) ? w2 : w3;
  int base = (bx & 1023) * 4096;
  double s = 0.0;
#pragma unroll
  for (int i = 0; i < 16; ++i)
    s += (double)fabsf(w[base + threadIdx.x + i * 256]);
  __shared__ double red[256];
  red[threadIdx.x] = s;
  __syncthreads();
  for (int off = 128; off; off >>= 1) {
    if (threadIdx.x < off) red[threadIdx.x] += red[threadIdx.x + off];
    __syncthreads();
  }
  if (threadIdx.x == 0) part[bx] = red[0];
}

__global__ __launch_bounds__(256) void k_wscale(const double* __restrict__ part,
                                                float* __restrict__ wsc) {
  int m = blockIdx.x, tid = threadIdx.x;
  const double* p = part + m * 1024;
  double s = p[tid] + p[tid + 256] + p[tid + 512] + p[tid + 768];
  __shared__ double red[256];
  red[tid] = s;
  __syncthreads();
  for (int off = 128; off; off >>= 1) {
    if (tid < off) red[tid] += red[tid + off];
    __syncthreads();
  }
  if (tid == 0) wsc[m] = (float)(red[0] / 4194304.0);
}

// ---------------- ternary quantize weights -> bf16 {-1,0,1} ----------------
__global__ __launch_bounds__(256) void k_wquant(const float* __restrict__ w0,
                                                const float* __restrict__ w1,
                                                const float* __restrict__ w2,
                                                const float* __restrict__ w3,
                                                const float* __restrict__ wsc,
                                                unsigned short* __restrict__ wt) {
  int mat = blockIdx.y;
  const float* w = (mat == 0) ? w0 : (mat == 1) ? w1 : (mat == 2) ? w2 : w3;
  float se = wsc[mat] + 1e-5f;
  size_t base = (size_t)blockIdx.x * 4096;
  unsigned short* o = wt + (size_t)mat * 4194304 + base;
  const float* wp = w + base;
#pragma unroll 4
  for (int i = 0; i < 16; ++i) {
    int idx = threadIdx.x + i * 256;
    float v = rintf(wp[idx] / se);
    v = fminf(fmaxf(v, -1.0f), 1.0f);
    o[idx] = f2bf(v);
  }
}

// ---------------- int4 row-quantize x -> bf16 ints + 1/s scale -------------
__global__ __launch_bounds__(256) void k_xquant(const float* __restrict__ x,
                                                unsigned short* __restrict__ xq,
                                                float* __restrict__ sx) {
  int row = blockIdx.x, tid = threadIdx.x;
  const float* xr = x + (size_t)row * 2048;
  float v[8];
  float mx = 0.0f;
#pragma unroll
  for (int i = 0; i < 8; ++i) {
    v[i] = xr[tid + i * 256];
    mx = fmaxf(mx, fabsf(v[i]));
  }
  __shared__ float red[256];
  red[tid] = mx;
  __syncthreads();
  for (int off = 128; off; off >>= 1) {
    if (tid < off) red[tid] = fmaxf(red[tid], red[tid + off]);
    __syncthreads();
  }
  float s = 7.0f / fmaxf(red[0], 1e-5f);
#pragma unroll
  for (int i = 0; i < 8; ++i) {
    float q = rintf(v[i] * s);
    q = fminf(fmaxf(q, -8.0f), 7.0f);
    xq[(size_t)row * 2048 + tid + i * 256] = f2bf(q);
  }
  if (tid == 0) sx[row] = s;
}

// ---------------- GEMM: C[i,j] = (sum xq[i,:]*wt[j,:]) * wscale / s_i ------
// 128x128 tile, BK=32, 4 waves, global_load_lds, bf16 MFMA (exact int math)
__global__ __launch_bounds__(256) void k_gemm(const unsigned short* __restrict__ A,
                                              const unsigned short* __restrict__ Bw,
                                              float* __restrict__ C,
                                              const float* __restrict__ srow,
                                              const float* __restrict__ wsp) {
  __shared__ unsigned short As[128 * 32];
  __shared__ unsigned short Bs[128 * 32];
  __shared__ float fac[128];
  const int tid = threadIdx.x, wave = tid >> 6, lane = tid & 63;
  const int brow = blockIdx.y * 128, bcol = blockIdx.x * 128;
  if (tid < 128) fac[tid] = wsp[0] / srow[brow + tid];
  const int wr = wave >> 1, wc = wave & 1;
  f32x4 acc[4][4];
#pragma unroll
  for (int m = 0; m < 4; ++m)
#pragma unroll
    for (int n = 0; n < 4; ++n) acc[m][n] = (f32x4){0.f, 0.f, 0.f, 0.f};
  const int srl = (wave << 4) + (lane >> 2);  // staged row 0..63
  const int scl = (lane & 3) * 8;             // staged k offset
  const unsigned short* Ag = A + (size_t)(brow + srl) * 2048 + scl;
  const unsigned short* Bg = Bw + (size_t)(bcol + srl) * 2048 + scl;
  char* AsB = (char*)As + wave * 1024;
  char* BsB = (char*)Bs + wave * 1024;
  const int fr = lane & 15, fk = (lane >> 4) << 3;
  for (int k0 = 0; k0 < 2048; k0 += 32) {
    __syncthreads();  // previous MFMA reads done
    GLDS16(Ag + k0, AsB);
    GLDS16(Ag + k0 + (size_t)64 * 2048, AsB + 4096);
    GLDS16(Bg + k0, BsB);
    GLDS16(Bg + k0 + (size_t)64 * 2048, BsB + 4096);
    __syncthreads();  // loads visible
    short8 af[4], bf[4];
#pragma unroll
    for (int m = 0; m < 4; ++m)
      af[m] = *(const short8*)&As[(wr * 64 + m * 16 + fr) * 32 + fk];
#pragma unroll
    for (int n = 0; n < 4; ++n)
      bf[n] = *(const short8*)&Bs[(wc * 64 + n * 16 + fr) * 32 + fk];
#pragma unroll
    for (int m = 0; m < 4; ++m)
#pragma unroll
      for (int n = 0; n < 4; ++n)
        acc[m][n] = __builtin_amdgcn_mfma_f32_16x16x32_bf16(af[m], bf[n],
                                                            acc[m][n], 0, 0, 0);
  }
  const int fq = lane >> 4;
#pragma unroll
  for (int m = 0; m < 4; ++m)
#pragma unroll
    for (int n = 0; n < 4; ++n)
#pragma unroll
      for (int r = 0; r < 4; ++r) {
        int row = wr * 64 + m * 16 + fq * 4 + r;
        C[(size_t)(brow + row) * 2048 + bcol + wc * 64 + n * 16 + fr] =
            acc[m][n][r] * fac[row];
      }
}

// ---------------- RoPE in-place on (B,T,D) q/k buffers ---------------------
__global__ __launch_bounds__(256) void k_rope(float* __restrict__ qb,
                                              float* __restrict__ kb,
                                              const float* __restrict__ ct,
                                              const float* __restrict__ st) {
  int idx = blockIdx.x * 256 + threadIdx.x;  // 4,194,304 pairs
  float* buf = blockIdx.y ? kb : qb;
  int hd = idx & 63;
  int h = (idx >> 6) & 15;
  int row = idx >> 10;  // 0..4095
  int t = row & 2047;
  size_t base = (size_t)row * 2048 + h * 128 + hd;
  float c = ct[t * 64 + hd], s = st[t * 64 + hd];
  float x1 = buf[base], x2 = buf[base + 64];
  buf[base] = x1 * c - x2 * s;
  buf[base + 64] = x2 * c + x1 * s;
}

// ---------------- MFMA flash attention (f16 hi/lo split) -------------------
// Block: 4 waves, 128 q rows (32/wave). K-tile = 32. 32x32x16 f16 MFMAs.
// S^T = mfma(A=K, B=Q): lane owns q=lane&31; softmax fully in-register.
// P repacked to PV A-frags via pair-pack + shfl_xor(32).
__global__ __launch_bounds__(256, 2) void k_attn(float* __restrict__ qb,
                                                 const float* __restrict__ kb,
                                                 const float* __restrict__ vg) {
  __shared__ alignas(16) _Float16 KhS[32 * 136];  // pad 136: 2-way reads
  __shared__ alignas(16) _Float16 KlS[32 * 136];
  __shared__ alignas(16) _Float16 VhS[128 * 40];  // V^T, pad 40
  __shared__ alignas(16) _Float16 VlS[128 * 40];
  const int tid = threadIdx.x;
  const int wave = tid >> 6, lane = tid & 63;
  const int rl = lane & 31, hi = lane >> 5, hi8 = hi * 8;
  const int bid = blockIdx.x;
  const int xcd = bid & 7, li = bid >> 3;            // XCD-aware: 4 bh per XCD
  const int bh = xcd * 4 + (li >> 4), qt = li & 15;  // bijective over 512
  const int b = bh >> 4, h = bh & 15;
  const size_t rowbase = (size_t)b * 2048;
  const int hcol = h * 128;
  const float SCALE = 0.08838834764831845f;  // 1/sqrt(128)

  // ---- Q fragments (hi/lo f16) in registers: q = qt*128 + wave*32 + rl ----
  f16x8 qh[8], ql[8];
  {
    const float* qsrc =
        qb + (rowbase + qt * 128 + wave * 32 + rl) * 2048 + hcol + hi8;
#pragma unroll
    for (int ds = 0; ds < 8; ++ds) {
      float4 a = *(const float4*)(qsrc + ds * 16);
      float4 c = *(const float4*)(qsrc + ds * 16 + 4);
      float v[8] = {a.x, a.y, a.z, a.w, c.x, c.y, c.z, c.w};
      f16x8 hh, ll;
#pragma unroll
      for (int i = 0; i < 8; ++i) {
        _Float16 hv = (_Float16)v[i];
        hh[i] = hv;
        ll[i] = (_Float16)(v[i] - (float)hv);
      }
      qh[ds] = hh;
      ql[ds] = ll;
    }
  }

  // staging roles
  const int kr = tid & 31, kseg = tid >> 5;       // K: row kr, d-chunk kseg*16
  const int vk = (tid & 15) * 2, vdg = tid >> 4;  // V: rows vk,vk+1, d vdg*8
  const float* kbase = kb + (rowbase + kr) * 2048 + hcol + kseg * 16;
  const float* vbase = vg + (rowbase + vk) * 2048 + hcol + vdg * 8;
  float4 kpre[4], vpre[4];
#pragma unroll
  for (int j = 0; j < 4; ++j) kpre[j] = *(const float4*)(kbase + j * 4);
  vpre[0] = *(const float4*)(vbase);
  vpre[1] = *(const float4*)(vbase + 4);
  vpre[2] = *(const float4*)(vbase + 2048);
  vpre[3] = *(const float4*)(vbase + 2048 + 4);

  f32x16 Oa[4];
#pragma unroll
  for (int df = 0; df < 4; ++df)
#pragma unroll
    for (int i = 0; i < 16; ++i) Oa[df][i] = 0.0f;
  float m = -INFINITY, lsum = 0.0f;

  for (int kt = 0; kt < 64; ++kt) {
    __syncthreads();  // prior tile's LDS reads complete
    {                 // ---- write staged K (hi/lo) ----
      float kf[16] = {kpre[0].x, kpre[0].y, kpre[0].z, kpre[0].w,
                      kpre[1].x, kpre[1].y, kpre[1].z, kpre[1].w,
                      kpre[2].x, kpre[2].y, kpre[2].z, kpre[2].w,
                      kpre[3].x, kpre[3].y, kpre[3].z, kpre[3].w};
#pragma unroll
      for (int j = 0; j < 2; ++j) {
        f16x8 hh, ll;
#pragma unroll
        for (int i = 0; i < 8; ++i) {
          float xv = kf[j * 8 + i];
          _Float16 hv = (_Float16)xv;
          hh[i] = hv;
          ll[i] = (_Float16)(xv - (float)hv);
        }
        *(f16x8*)&KhS[kr * 136 + kseg * 16 + j * 8] = hh;
        *(f16x8*)&KlS[kr * 136 + kseg * 16 + j * 8] = ll;
      }
    }
    {  // ---- write staged V^T (packed k-pairs) ----
      float va[8] = {vpre[0].x, vpre[0].y, vpre[0].z, vpre[0].w,
                     vpre[1].x, vpre[1].y, vpre[1].z, vpre[1].w};
      float vb[8] = {vpre[2].x, vpre[2].y, vpre[2].z, vpre[2].w,
                     vpre[3].x, vpre[3].y, vpre[3].z, vpre[3].w};
#pragma unroll
      for (int i = 0; i < 8; ++i) {
        int d = vdg * 8 + i;
        _Float16 ah = (_Float16)va[i], bh = (_Float16)vb[i];
        *(unsigned int*)&VhS[d * 40 + vk] = pk2(ah, bh);
        _Float16 al = (_Float16)(va[i] - (float)ah);
        _Float16 bl = (_Float16)(vb[i] - (float)bh);
        *(unsigned int*)&VlS[d * 40 + vk] = pk2(al, bl);
      }
    }
    __syncthreads();  // staged data visible
    if (kt < 63) {    // ---- prefetch next K/V tile (T14) ----
      const float* kn = kbase + (size_t)(kt + 1) * 32 * 2048;
      const float* vn = vbase + (size_t)(kt + 1) * 32 * 2048;
#pragma unroll
      for (int j = 0; j < 4; ++j) kpre[j] = *(const float4*)(kn + j * 4);
      vpre[0] = *(const float4*)(vn);
      vpre[1] = *(const float4*)(vn + 4);
      vpre[2] = *(const float4*)(vn + 2048);
      vpre[3] = *(const float4*)(vn + 2048 + 4);
    }
    // ---- QK^T: S^T[k][q], 3-way f16 split ----
    f32x16 s = {};
#pragma unroll
    for (int ds = 0; ds < 8; ++ds) {
      f16x8 kh = *(const f16x8*)&KhS[rl * 136 + ds * 16 + hi8];
      f16x8 kl = *(const f16x8*)&KlS[rl * 136 + ds * 16 + hi8];
      s = __builtin_amdgcn_mfma_f32_32x32x16_f16(kh, qh[ds], s, 0, 0, 0);
      s = __builtin_amdgcn_mfma_f32_32x32x16_f16(kh, ql[ds], s, 0, 0, 0);
      s = __builtin_amdgcn_mfma_f32_32x32x16_f16(kl, qh[ds], s, 0, 0, 0);
    }
    // ---- online softmax, fully in-register (lane owns q=rl) ----
    float pm = s[0];
#pragma unroll
    for (int r = 1; r < 16; ++r) pm = fmaxf(pm, s[r]);
    pm = fmaxf(pm, __shfl_xor(pm, 32));
    float mn = fmaxf(m, pm * SCALE);
    float alpha = expf(m - mn);
    m = mn;
    unsigned int pkh[4][2], pkl[4][2];
    float ls = 0.0f;
#pragma unroll
    for (int t = 0; t < 4; ++t)
#pragma unroll
      for (int c2 = 0; c2 < 2; ++c2) {
        float pa = expf(s[4 * t + 2 * c2] * SCALE - mn);
        float pb = expf(s[4 * t + 2 * c2 + 1] * SCALE - mn);
        ls += pa + pb;
        _Float16 pah = (_Float16)pa, pbh = (_Float16)pb;
        pkh[t][c2] = pk2(pah, pbh);
        pkl[t][c2] = pk2((_Float16)(pa - (float)pah), (_Float16)(pb - (float)pbh));
      }
    ls += __shfl_xor(ls, 32);
    lsum = lsum * alpha + ls;
    // ---- rescale O by alpha (broadcast per output row) ----
#pragma unroll
    for (int reg = 0; reg < 16; ++reg) {
      int qr = (reg & 3) + 8 * (reg >> 2) + 4 * hi;
      float av = __shfl(alpha, qr);
      Oa[0][reg] *= av;
      Oa[1][reg] *= av;
      Oa[2][reg] *= av;
      Oa[3][reg] *= av;
    }
    // ---- build PV A-frags: exchange halves (k from partner lane^32) ----
    f16x8 paH[2], paL[2];
#pragma unroll
    for (int hf = 0; hf < 2; ++hf) {
      unsigned int curh0 = hi ? pkh[2 * hf + 1][0] : pkh[2 * hf][0];
      unsigned int curh1 = hi ? pkh[2 * hf + 1][1] : pkh[2 * hf][1];
      unsigned int othh0 = hi ? pkh[2 * hf][0] : pkh[2 * hf + 1][0];
      unsigned int othh1 = hi ? pkh[2 * hf][1] : pkh[2 * hf + 1][1];
      unsigned int xh0 = (unsigned int)__shfl_xor((int)othh0, 32);
      unsigned int xh1 = (unsigned int)__shfl_xor((int)othh1, 32);
      uint4 uh;
      uh.x = hi ? xh0 : curh0;
      uh.y = hi ? xh1 : curh1;
      uh.z = hi ? curh0 : xh0;
      uh.w = hi ? curh1 : xh1;
      paH[hf] = __builtin_bit_cast(f16x8, uh);
      unsigned int curl0 = hi ? pkl[2 * hf + 1][0] : pkl[2 * hf][0];
      unsigned int curl1 = hi ? pkl[2 * hf + 1][1] : pkl[2 * hf][1];
      unsigned int othl0 = hi ? pkl[2 * hf][0] : pkl[2 * hf + 1][0];
      unsigned int othl1 = hi ? pkl[2 * hf][1] : pkl[2 * hf + 1][1];
      unsigned int xl0 = (unsigned int)__shfl_xor((int)othl0, 32);
      unsigned int xl1 = (unsigned int)__shfl_xor((int)othl1, 32);
      uint4 ul;
      ul.x = hi ? xl0 : curl0;
      ul.y = hi ? xl1 : curl1;
      ul.z = hi ? curl0 : xl0;
      ul.w = hi ? curl1 : xl1;
      paL[hf] = __builtin_bit_cast(f16x8, ul);
    }
    // ---- PV: O += P @ V (3-way split) ----
#pragma unroll
    for (int df = 0; df < 4; ++df) {
#pragma unroll
      for (int hf = 0; hf < 2; ++hf) {
        f16x8 vh = *(const f16x8*)&VhS[(df * 32 + rl) * 40 + hf * 16 + hi8];
        f16x8 vl = *(const f16x8*)&VlS[(df * 32 + rl) * 40 + hf * 16 + hi8];
        Oa[df] = __builtin_amdgcn_mfma_f32_32x32x16_f16(paH[hf], vh, Oa[df], 0, 0, 0);
        Oa[df] = __builtin_amdgcn_mfma_f32_32x32x16_f16(paH[hf], vl, Oa[df], 0, 0, 0);
        Oa[df] = __builtin_amdgcn_mfma_f32_32x32x16_f16(paL[hf], vh, Oa[df], 0, 0, 0);
      }
    }
  }
  // ---- epilogue: divide by l, store (in-place into qb rows we own) ----
  float linv = 1.0f / lsum;
  float* obase = qb + (rowbase + qt * 128 + wave * 32) * 2048 + hcol;
#pragma unroll
  for (int reg = 0; reg < 16; ++reg) {
    int qr = (reg & 3) + 8 * (reg >> 2) + 4 * hi;
    float lv = __shfl(linv, qr);
    float* orow = obase + (size_t)qr * 2048;
    orow[0 * 32 + rl] = Oa[0][reg] * lv;
    orow[1 * 32 + rl] = Oa[1][reg] * lv;
    orow[2 * 32 + rl] = Oa[2][reg] * lv;
    orow[3 * 32 + rl] = Oa[3][reg] * lv;
  }
}

// ---------------- topk(0.55)+int8 quantize per row (exact tie handling) ----
__global__ __launch_bounds__(256) void k_topk(const float* __restrict__ ain,
                                              unsigned short* __restrict__ oq,
                                              float* __restrict__ so) {
  const int row = blockIdx.x, tid = threadIdx.x;
  const float* xr = ain + (size_t)row * 2048;
  __shared__ unsigned int bits[2048];
  __shared__ unsigned int hist[256];
  __shared__ unsigned int scn[256];
  __shared__ unsigned int stat[3];  // prefix, rk, maxbits
#pragma unroll
  for (int j = 0; j < 8; ++j) {
    int i = tid * 8 + j;
    bits[i] = __float_as_uint(xr[i]) & 0x7fffffffu;
  }
  unsigned int mx = 0;
#pragma unroll
  for (int j = 0; j < 8; ++j) mx = max(mx, bits[tid * 8 + j]);
  scn[tid] = mx;
  __syncthreads();
  for (int off = 128; off; off >>= 1) {
    if (tid < off) scn[tid] = max(scn[tid], scn[tid + off]);
    __syncthreads();
  }
  if (tid == 0) { stat[0] = 0u; stat[1] = 1126u; stat[2] = scn[0]; }
  // 4-pass radix select (exact 32-bit threshold)
  for (int p = 0; p < 4; ++p) {
    const int shift = 24 - 8 * p;
    hist[tid] = 0u;
    __syncthreads();
    unsigned int pref = stat[0];
    unsigned int rk0 = stat[1];
#pragma unroll
    for (int j = 0; j < 8; ++j) {
      unsigned int u = bits[tid * 8 + j];
      bool match = (p == 0) || ((u >> (shift + 8)) == pref);
      if (match) atomicAdd(&hist[(u >> shift) & 255u], 1u);
    }
    __syncthreads();
    // suffix sums: scn[b] = sum_{bb>=b} hist[bb]
    scn[tid] = hist[tid];
    __syncthreads();
    for (int off = 1; off < 256; off <<= 1) {
      unsigned int v = (tid + off < 256) ? scn[tid + off] : 0u;
      __syncthreads();
      scn[tid] += v;
      __syncthreads();
    }
    unsigned int nxt = (tid == 255) ? 0u : scn[tid + 1];
    if (scn[tid] >= rk0 && nxt < rk0) {
      stat[0] = (pref << 8) | (unsigned int)tid;
      stat[1] = rk0 - nxt;
    }
    __syncthreads();
  }
  const unsigned int T = stat[0];
  const unsigned int rkeep = stat[1];
  const float rowmax = __uint_as_float(stat[2]);
  const float s = 127.0f / fmaxf(rowmax, 1e-5f);
  // rank-among-equals (index order), exclusive prefix over contiguous chunks
  unsigned int cnt = 0;
#pragma unroll
  for (int j = 0; j < 8; ++j) cnt += (bits[tid * 8 + j] == T) ? 1u : 0u;
  scn[tid] = cnt;
  __syncthreads();
  for (int off = 1; off < 256; off <<= 1) {
    unsigned int v = (tid >= off) ? scn[tid - off] : 0u;
    __syncthreads();
    scn[tid] += v;
    __syncthreads();
  }
  unsigned int eqr = scn[tid] - cnt;
#pragma unroll
  for (int j = 0; j < 8; ++j) {
    int i = tid * 8 + j;
    unsigned int u = bits[i];
    bool keep = u > T;
    if (u == T) { keep = (eqr < rkeep); eqr++; }
    float q = 0.0f;
    if (keep) {
      q = rintf(xr[i] * s);
      q = fminf(fmaxf(q, -128.0f), 127.0f);
    }
    oq[(size_t)row * 2048 + i] = f2bf(q);
  }
  if (tid == 0) so[row] = s;
}

// ---------------------------------------------------------------------------
extern "C" void kernel_launch(void* const* d_in, const int* in_sizes, int n_in,
                              void* d_out, int out_size, void* d_ws,
                              size_t ws_size, hipStream_t stream) {
  const float* x = (const float*)d_in[0];
  const float* wq = (const float*)d_in[1];
  const float* wk = (const float*)d_in[2];
  const float* wv = (const float*)d_in[3];
  const float* wo = (const float*)d_in[4];
  float* out = (float*)d_out;

  char* ws = (char*)d_ws;
  size_t off = 0;
  auto alloc = [&](size_t bytes) -> void* {
    void* p = ws + off;
    off += (bytes + 255) & ~(size_t)255;
    return p;
  };
  unsigned short* wt = (unsigned short*)alloc(4ull * 2048 * 2048 * 2);  // 33.5MB
  unsigned short* xq = (unsigned short*)alloc(4096ull * 2048 * 2);      // 16.8MB
  float* qb = (float*)alloc(4096ull * 2048 * 4);                        // 33.5MB
  float* kb = (float*)alloc(4096ull * 2048 * 4);
  float* vb = (float*)alloc(4096ull * 2048 * 4);
  float* ct = (float*)alloc(2048ull * 64 * 4);
  float* st = (float*)alloc(2048ull * 64 * 4);
  float* sx = (float*)alloc(4096 * 4);
  float* so = (float*)alloc(4096 * 4);
  float* wsc = (float*)alloc(4 * 4);
  double* prt = (double*)alloc(4096 * 8);
  unsigned short* oq = (unsigned short*)vb;  // overlay: vb dead after attention

  k_costab<<<512, 256, 0, stream>>>(ct, st);
  k_wsum<<<4096, 256, 0, stream>>>(wq, wk, wv, wo, prt);
  k_wscale<<<4, 256, 0, stream>>>(prt, wsc);
  k_wquant<<<dim3(1024, 4), 256, 0, stream>>>(wq, wk, wv, wo, wsc, wt);
  k_xquant<<<4096, 256, 0, stream>>>(x, xq, sx);

  dim3 gg(16, 32);
  k_gemm<<<gg, 256, 0, stream>>>(xq, wt + 0ull * 4194304, qb, sx, wsc + 0);
  k_gemm<<<gg, 256, 0, stream>>>(xq, wt + 1ull * 4194304, kb, sx, wsc + 1);
  k_gemm<<<gg, 256, 0, stream>>>(xq, wt + 2ull * 4194304, vb, sx, wsc + 2);

  k_rope<<<dim3(16384, 2), 256, 0, stream>>>(qb, kb, ct, st);
  k_attn<<<512, 256, 0, stream>>>(qb, kb, vb);  // out -> qb in-place
  k_topk<<<4096, 256, 0, stream>>>(qb, oq, so);
  k_gemm<<<gg, 256, 0, stream>>>(oq, wt + 3ull * 4194304, out, so, wsc + 3);
}

// Round 3
// 539.159 us; speedup vs baseline: 3.9972x; 1.0906x over previous
//
#include <hip/hip_runtime.h>
#include <stdint.h>
#include <math.h>

// ---------------------------------------------------------------------------
// BitAttention: B=2, T=2048, D=2048, H=16, HD=128
//   q/k/v = int4-quant(x) @ ternary(w)^T   (exact integer math via bf16 MFMA)
//   rope(q), rope(k); MFMA flash attention (f16 hi/lo split ~ f32 accurate,
//   producer-split planes, defer-max, double-buffered LDS)
//   out = int8-quant(topk_0.55(attn)) @ ternary(wo)^T (exact int via MFMA)
// ---------------------------------------------------------------------------

typedef __attribute__((ext_vector_type(8))) short short8;
typedef __attribute__((ext_vector_type(4))) float f32x4;
typedef __attribute__((ext_vector_type(8))) _Float16 f16x8;
typedef __attribute__((ext_vector_type(16))) float f32x16;

#define GLDS16(g, l)                                                        \
  __builtin_amdgcn_global_load_lds(                                         \
      (const __attribute__((address_space(1))) void*)(g),                   \
      (__attribute__((address_space(3))) void*)(l), 16, 0, 0)

__device__ __forceinline__ unsigned short f2bf(float v) {
  // exact for the small-integer values we store
  return (unsigned short)(__float_as_uint(v) >> 16);
}

__device__ __forceinline__ unsigned int pk2(_Float16 a, _Float16 b) {
  return (unsigned int)__builtin_bit_cast(unsigned short, a) |
         ((unsigned int)__builtin_bit_cast(unsigned short, b) << 16);
}

// ---------------- cos/sin tables (T x 64), faithful f32 path ---------------
__global__ __launch_bounds__(256) void k_costab(float* __restrict__ ct,
                                                float* __restrict__ st) {
  int idx = blockIdx.x * 256 + threadIdx.x;  // 2048*64
  int t = idx >> 6, i = idx & 63;
  float f = (float)(2 * i) / 128.0f;
  float inv = 1.0f / powf(10000.0f, f);
  float fr = (float)t * inv;
  ct[idx] = cosf(fr);
  st[idx] = sinf(fr);
}

// ---------------- weight scale: mean(|w|), deterministic f64 tree ----------
__global__ __launch_bounds__(256) void k_wsum(const float* __restrict__ w0,
                                              const float* __restrict__ w1,
                                              const float* __restrict__ w2,
                                              const float* __restrict__ w3,
                                              double* __restrict__ part) {
  int bx = blockIdx.x;  // 0..4095 ; 1024 blocks per matrix
  int mat = bx >> 10;
  const float* w = (mat == 0) ? w0 : (mat == 1) ? w1 : (mat == 2) ? w2 : w3;
  int base = (bx & 1023) * 4096;
  double s = 0.0;
#pragma unroll
  for (int i = 0; i < 16; ++i)
    s += (double)fabsf(w[base + threadIdx.x + i * 256]);
  __shared__ double red[256];
  red[threadIdx.x] = s;
  __syncthreads();
  for (int off = 128; off; off >>= 1) {
    if (threadIdx.x < off) red[threadIdx.x] += red[threadIdx.x + off];
    __syncthreads();
  }
  if (threadIdx.x == 0) part[bx] = red[0];
}

__global__ __launch_bounds__(256) void k_wscale(const double* __restrict__ part,
                                                float* __restrict__ wsc) {
  int m = blockIdx.x, tid = threadIdx.x;
  const double* p = part + m * 1024;
  double s = p[tid] + p[tid + 256] + p[tid + 512] + p[tid + 768];
  __shared__ double red[256];
  red[tid] = s;
  __syncthreads();
  for (int off = 128; off; off >>= 1) {
    if (tid < off) red[tid] += red[tid + off];
    __syncthreads();
  }
  if (tid == 0) wsc[m] = (float)(red[0] / 4194304.0);
}

// ---------------- ternary quantize weights -> bf16 {-1,0,1} ----------------
__global__ __launch_bounds__(256) void k_wquant(const float* __restrict__ w0,
                                                const float* __restrict__ w1,
                                                const float* __restrict__ w2,
                                                const float* __restrict__ w3,
                                                const float* __restrict__ wsc,
                                                unsigned short* __restrict__ wt) {
  int mat = blockIdx.y;
  const float* w = (mat == 0) ? w0 : (mat == 1) ? w1 : (mat == 2) ? w2 : w3;
  float se = wsc[mat] + 1e-5f;
  size_t base = (size_t)blockIdx.x * 4096;
  unsigned short* o = wt + (size_t)mat * 4194304 + base;
  const float* wp = w + base;
#pragma unroll 4
  for (int i = 0; i < 16; ++i) {
    int idx = threadIdx.x + i * 256;
    float v = rintf(wp[idx] / se);
    v = fminf(fmaxf(v, -1.0f), 1.0f);
    o[idx] = f2bf(v);
  }
}

// ---------------- int4 row-quantize x -> bf16 ints + 1/s scale -------------
__global__ __launch_bounds__(256) void k_xquant(const float* __restrict__ x,
                                                unsigned short* __restrict__ xq,
                                                float* __restrict__ sx) {
  int row = blockIdx.x, tid = threadIdx.x;
  const float* xr = x + (size_t)row * 2048;
  float v[8];
  float mx = 0.0f;
#pragma unroll
  for (int i = 0; i < 8; ++i) {
    v[i] = xr[tid + i * 256];
    mx = fmaxf(mx, fabsf(v[i]));
  }
  __shared__ float red[256];
  red[tid] = mx;
  __syncthreads();
  for (int off = 128; off; off >>= 1) {
    if (tid < off) red[tid] = fmaxf(red[tid], red[tid + off]);
    __syncthreads();
  }
  float s = 7.0f / fmaxf(red[0], 1e-5f);
#pragma unroll
  for (int i = 0; i < 8; ++i) {
    float q = rintf(v[i] * s);
    q = fminf(fmaxf(q, -8.0f), 7.0f);
    xq[(size_t)row * 2048 + tid + i * 256] = f2bf(q);
  }
  if (tid == 0) sx[row] = s;
}

// ---------------- fused QKV GEMM: 3 weight mats, shared A ------------------
// 128x128 tile, BK=32, 4 waves, global_load_lds, bf16 MFMA (exact int math)
__global__ __launch_bounds__(256) void k_gemm3(const unsigned short* __restrict__ A,
                                               const unsigned short* __restrict__ wtall,
                                               float* __restrict__ qo,
                                               float* __restrict__ ko,
                                               float* __restrict__ vo,
                                               const float* __restrict__ srow,
                                               const float* __restrict__ wsc) {
  __shared__ unsigned short As[128 * 32];
  __shared__ unsigned short Bs[128 * 32];
  __shared__ float fac[128];
  const int tid = threadIdx.x, wave = tid >> 6, lane = tid & 63;
  const int bxi = blockIdx.x;
  const int mat = bxi >> 4;
  const unsigned short* Bw = wtall + (size_t)mat * 4194304;
  float* C = (mat == 0) ? qo : (mat == 1) ? ko : vo;
  const int brow = blockIdx.y * 128, bcol = (bxi & 15) * 128;
  if (tid < 128) fac[tid] = wsc[mat] / srow[brow + tid];
  const int wr = wave >> 1, wc = wave & 1;
  f32x4 acc[4][4];
#pragma unroll
  for (int m = 0; m < 4; ++m)
#pragma unroll
    for (int n = 0; n < 4; ++n) acc[m][n] = (f32x4){0.f, 0.f, 0.f, 0.f};
  const int srl = (wave << 4) + (lane >> 2);
  const int scl = (lane & 3) * 8;
  const unsigned short* Ag = A + (size_t)(brow + srl) * 2048 + scl;
  const unsigned short* Bg = Bw + (size_t)(bcol + srl) * 2048 + scl;
  char* AsB = (char*)As + wave * 1024;
  char* BsB = (char*)Bs + wave * 1024;
  const int fr = lane & 15, fk = (lane >> 4) << 3;
  for (int k0 = 0; k0 < 2048; k0 += 32) {
    __syncthreads();
    GLDS16(Ag + k0, AsB);
    GLDS16(Ag + k0 + (size_t)64 * 2048, AsB + 4096);
    GLDS16(Bg + k0, BsB);
    GLDS16(Bg + k0 + (size_t)64 * 2048, BsB + 4096);
    __syncthreads();
    short8 af[4], bf[4];
#pragma unroll
    for (int m = 0; m < 4; ++m)
      af[m] = *(const short8*)&As[(wr * 64 + m * 16 + fr) * 32 + fk];
#pragma unroll
    for (int n = 0; n < 4; ++n)
      bf[n] = *(const short8*)&Bs[(wc * 64 + n * 16 + fr) * 32 + fk];
#pragma unroll
    for (int m = 0; m < 4; ++m)
#pragma unroll
      for (int n = 0; n < 4; ++n)
        acc[m][n] = __builtin_amdgcn_mfma_f32_16x16x32_bf16(af[m], bf[n],
                                                            acc[m][n], 0, 0, 0);
  }
  const int fq = lane >> 4;
#pragma unroll
  for (int m = 0; m < 4; ++m)
#pragma unroll
    for (int n = 0; n < 4; ++n)
#pragma unroll
      for (int r = 0; r < 4; ++r) {
        int row = wr * 64 + m * 16 + fq * 4 + r;
        C[(size_t)(brow + row) * 2048 + bcol + wc * 64 + n * 16 + fr] =
            acc[m][n][r] * fac[row];
      }
}

// ---------------- single GEMM (output projection) --------------------------
__global__ __launch_bounds__(256) void k_gemm(const unsigned short* __restrict__ A,
                                              const unsigned short* __restrict__ Bw,
                                              float* __restrict__ C,
                                              const float* __restrict__ srow,
                                              const float* __restrict__ wsp) {
  __shared__ unsigned short As[128 * 32];
  __shared__ unsigned short Bs[128 * 32];
  __shared__ float fac[128];
  const int tid = threadIdx.x, wave = tid >> 6, lane = tid & 63;
  const int brow = blockIdx.y * 128, bcol = blockIdx.x * 128;
  if (tid < 128) fac[tid] = wsp[0] / srow[brow + tid];
  const int wr = wave >> 1, wc = wave & 1;
  f32x4 acc[4][4];
#pragma unroll
  for (int m = 0; m < 4; ++m)
#pragma unroll
    for (int n = 0; n < 4; ++n) acc[m][n] = (f32x4){0.f, 0.f, 0.f, 0.f};
  const int srl = (wave << 4) + (lane >> 2);
  const int scl = (lane & 3) * 8;
  const unsigned short* Ag = A + (size_t)(brow + srl) * 2048 + scl;
  const unsigned short* Bg = Bw + (size_t)(bcol + srl) * 2048 + scl;
  char* AsB = (char*)As + wave * 1024;
  char* BsB = (char*)Bs + wave * 1024;
  const int fr = lane & 15, fk = (lane >> 4) << 3;
  for (int k0 = 0; k0 < 2048; k0 += 32) {
    __syncthreads();
    GLDS16(Ag + k0, AsB);
    GLDS16(Ag + k0 + (size_t)64 * 2048, AsB + 4096);
    GLDS16(Bg + k0, BsB);
    GLDS16(Bg + k0 + (size_t)64 * 2048, BsB + 4096);
    __syncthreads();
    short8 af[4], bf[4];
#pragma unroll
    for (int m = 0; m < 4; ++m)
      af[m] = *(const short8*)&As[(wr * 64 + m * 16 + fr) * 32 + fk];
#pragma unroll
    for (int n = 0; n < 4; ++n)
      bf[n] = *(const short8*)&Bs[(wc * 64 + n * 16 + fr) * 32 + fk];
#pragma unroll
    for (int m = 0; m < 4; ++m)
#pragma unroll
      for (int n = 0; n < 4; ++n)
        acc[m][n] = __builtin_amdgcn_mfma_f32_16x16x32_bf16(af[m], bf[n],
                                                            acc[m][n], 0, 0, 0);
  }
  const int fq = lane >> 4;
#pragma unroll
  for (int m = 0; m < 4; ++m)
#pragma unroll
    for (int n = 0; n < 4; ++n)
#pragma unroll
      for (int r = 0; r < 4; ++r) {
        int row = wr * 64 + m * 16 + fq * 4 + r;
        C[(size_t)(brow + row) * 2048 + bcol + wc * 64 + n * 16 + fr] =
            acc[m][n][r] * fac[row];
      }
}

// ---------------- V^T transpose to f16 hi/lo planes [bh][128][2048] --------
__global__ __launch_bounds__(256) void k_vtrans(const float* __restrict__ vb,
                                                _Float16* __restrict__ vth,
                                                _Float16* __restrict__ vtl) {
  __shared__ float F[64][133];
  const int tid = threadIdx.x;
  const int bh = blockIdx.y, b = bh >> 4, h = bh & 15;
  const int t0 = blockIdx.x * 64;
  {
    const int tr = tid >> 2, tc = (tid & 3) * 32;
    const float* src = vb + ((size_t)(b * 2048 + t0 + tr)) * 2048 + h * 128 + tc;
#pragma unroll
    for (int j = 0; j < 8; ++j) {
      float4 v = *(const float4*)(src + j * 4);
      F[tr][tc + j * 4 + 0] = v.x;
      F[tr][tc + j * 4 + 1] = v.y;
      F[tr][tc + j * 4 + 2] = v.z;
      F[tr][tc + j * 4 + 3] = v.w;
    }
  }
  __syncthreads();
  {
    const int vd = tid >> 1, th = (tid & 1) * 32;
    f16x8 oh[4], ol[4];
#pragma unroll
    for (int j = 0; j < 32; ++j) {
      float x = F[th + j][vd];
      _Float16 hv = (_Float16)x;
      oh[j >> 3][j & 7] = hv;
      ol[j >> 3][j & 7] = (_Float16)(x - (float)hv);
    }
    _Float16* dh = vth + ((size_t)bh * 128 + vd) * 2048 + t0 + th;
    _Float16* dl = vtl + ((size_t)bh * 128 + vd) * 2048 + t0 + th;
#pragma unroll
    for (int j4 = 0; j4 < 4; ++j4) {
      *(f16x8*)(dh + j4 * 8) = oh[j4];
      *(f16x8*)(dl + j4 * 8) = ol[j4];
    }
  }
}

// ---------------- RoPE: Q in-place f32; K -> f16 hi/lo planes [bh][t][128] -
__global__ __launch_bounds__(256) void k_rope(float* __restrict__ qb,
                                              const float* __restrict__ kb,
                                              _Float16* __restrict__ kh,
                                              _Float16* __restrict__ kl,
                                              const float* __restrict__ ct,
                                              const float* __restrict__ st) {
  int idx = blockIdx.x * 256 + threadIdx.x;  // 4,194,304 pairs
  int hd = idx & 63;
  int h = (idx >> 6) & 15;
  int row = idx >> 10;  // 0..4095
  int t = row & 2047;
  float c = ct[t * 64 + hd], s = st[t * 64 + hd];
  if (blockIdx.y == 0) {
    float* p = qb + (size_t)row * 2048 + h * 128 + hd;
    float x1 = p[0], x2 = p[64];
    p[0] = x1 * c - x2 * s;
    p[64] = x2 * c + x1 * s;
  } else {
    const float* p = kb + (size_t)row * 2048 + h * 128 + hd;
    float x1 = p[0], x2 = p[64];
    float y1 = x1 * c - x2 * s;
    float y2 = x2 * c + x1 * s;
    int b = row >> 11;
    size_t obase = ((size_t)(b * 16 + h) * 2048 + t) * 128 + hd;
    _Float16 h1 = (_Float16)y1, h2 = (_Float16)y2;
    kh[obase] = h1;
    kh[obase + 64] = h2;
    kl[obase] = (_Float16)(y1 - (float)h1);
    kl[obase + 64] = (_Float16)(y2 - (float)h2);
  }
}

// ---------------- MFMA flash attention --------------------------------------
// 4 waves, 128 q rows/block. K-tile 32, 32x32x16 f16 MFMAs, hi/lo 3-term split.
// Producer-split K/V planes -> staging is pure copy. Defer-max THR=8.
// Double-buffered LDS: 1 barrier/tile.
__global__ __launch_bounds__(256, 2) void k_attn(float* __restrict__ qb,
                                                 const _Float16* __restrict__ kh,
                                                 const _Float16* __restrict__ kl,
                                                 const _Float16* __restrict__ vth,
                                                 const _Float16* __restrict__ vtl) {
  __shared__ alignas(16) _Float16 KhS[2][32 * 136];
  __shared__ alignas(16) _Float16 KlS[2][32 * 136];
  __shared__ alignas(16) _Float16 VhS[2][128 * 40];
  __shared__ alignas(16) _Float16 VlS[2][128 * 40];
  const int tid = threadIdx.x;
  const int wave = tid >> 6, lane = tid & 63;
  const int rl = lane & 31, hi = lane >> 5, hi8 = hi * 8;
  const int bid = blockIdx.x;
  const int xcd = bid & 7, li = bid >> 3;            // XCD-aware: 4 bh per XCD
  const int bh = xcd * 4 + (li >> 4), qt = li & 15;  // bijective over 512
  const int b = bh >> 4, h = bh & 15;
  const size_t rowbase = (size_t)b * 2048;
  const int hcol = h * 128;
  const float SCALE = 0.08838834764831845f;  // 1/sqrt(128)

  // ---- Q fragments (hi/lo f16, SCALE prefolded) ----
  f16x8 qh[8], ql[8];
  {
    const float* qsrc =
        qb + (rowbase + qt * 128 + wave * 32 + rl) * 2048 + hcol + hi8;
#pragma unroll
    for (int ds = 0; ds < 8; ++ds) {
      float4 a = *(const float4*)(qsrc + ds * 16);
      float4 c = *(const float4*)(qsrc + ds * 16 + 4);
      float v[8] = {a.x, a.y, a.z, a.w, c.x, c.y, c.z, c.w};
      f16x8 hh, ll;
#pragma unroll
      for (int i = 0; i < 8; ++i) {
        float sv = v[i] * SCALE;
        _Float16 hv = (_Float16)sv;
        hh[i] = hv;
        ll[i] = (_Float16)(sv - (float)hv);
      }
      qh[ds] = hh;
      ql[ds] = ll;
    }
  }

  // staging roles (pure copies)
  const int kr = tid >> 3, kseg = tid & 7;         // K row, 16-f16 d-chunk
  const int vd = tid >> 1, th16 = (tid & 1) * 16;  // V^T d-row, t-chunk
  const _Float16* kbh = kh + ((size_t)bh * 2048 + kr) * 128 + kseg * 16;
  const _Float16* kbl = kl + ((size_t)bh * 2048 + kr) * 128 + kseg * 16;
  const _Float16* vbh = vth + ((size_t)bh * 128 + vd) * 2048 + th16;
  const _Float16* vbl = vtl + ((size_t)bh * 128 + vd) * 2048 + th16;

  f16x8 pkh0 = *(const f16x8*)(kbh), pkh1 = *(const f16x8*)(kbh + 8);
  f16x8 pkl0 = *(const f16x8*)(kbl), pkl1 = *(const f16x8*)(kbl + 8);
  f16x8 pvh0 = *(const f16x8*)(vbh), pvh1 = *(const f16x8*)(vbh + 8);
  f16x8 pvl0 = *(const f16x8*)(vbl), pvl1 = *(const f16x8*)(vbl + 8);

  f32x16 Oa[4];
#pragma unroll
  for (int df = 0; df < 4; ++df)
#pragma unroll
    for (int i = 0; i < 16; ++i) Oa[df][i] = 0.0f;
  float m = -INFINITY, lsum = 0.0f;

  for (int kt = 0; kt < 64; ++kt) {
    const int bf = kt & 1;
    // ---- write staged tile into buf[bf] (other buffer is being computed) --
    *(f16x8*)&KhS[bf][kr * 136 + kseg * 16] = pkh0;
    *(f16x8*)&KhS[bf][kr * 136 + kseg * 16 + 8] = pkh1;
    *(f16x8*)&KlS[bf][kr * 136 + kseg * 16] = pkl0;
    *(f16x8*)&KlS[bf][kr * 136 + kseg * 16 + 8] = pkl1;
    *(f16x8*)&VhS[bf][vd * 40 + th16] = pvh0;
    *(f16x8*)&VhS[bf][vd * 40 + th16 + 8] = pvh1;
    *(f16x8*)&VlS[bf][vd * 40 + th16] = pvl0;
    *(f16x8*)&VlS[bf][vd * 40 + th16 + 8] = pvl1;
    if (kt < 63) {  // ---- prefetch next tile into regs (T14) ----
      const _Float16* nkh = kbh + (size_t)(kt + 1) * 4096;
      const _Float16* nkl = kbl + (size_t)(kt + 1) * 4096;
      const _Float16* nvh = vbh + (size_t)(kt + 1) * 32;
      const _Float16* nvl = vbl + (size_t)(kt + 1) * 32;
      pkh0 = *(const f16x8*)(nkh);
      pkh1 = *(const f16x8*)(nkh + 8);
      pkl0 = *(const f16x8*)(nkl);
      pkl1 = *(const f16x8*)(nkl + 8);
      pvh0 = *(const f16x8*)(nvh);
      pvh1 = *(const f16x8*)(nvh + 8);
      pvl0 = *(const f16x8*)(nvl);
      pvl1 = *(const f16x8*)(nvl + 8);
    }
    __syncthreads();  // staged writes visible; prev compute done
    // ---- QK^T: S^T[k][q] (scaled), 3-term split ----
    f32x16 s = {};
#pragma unroll
    for (int ds = 0; ds < 8; ++ds) {
      f16x8 ah = *(const f16x8*)&KhS[bf][rl * 136 + ds * 16 + hi8];
      f16x8 al = *(const f16x8*)&KlS[bf][rl * 136 + ds * 16 + hi8];
      s = __builtin_amdgcn_mfma_f32_32x32x16_f16(ah, qh[ds], s, 0, 0, 0);
      s = __builtin_amdgcn_mfma_f32_32x32x16_f16(ah, ql[ds], s, 0, 0, 0);
      s = __builtin_amdgcn_mfma_f32_32x32x16_f16(al, qh[ds], s, 0, 0, 0);
    }
    // ---- online softmax, defer-max (THR=8) ----
    float pm = s[0];
#pragma unroll
    for (int r = 1; r < 16; ++r) pm = fmaxf(pm, s[r]);
    pm = fmaxf(pm, __shfl_xor(pm, 32));
    float alpha = 1.0f;
    if (__any(pm > m + 8.0f)) {  // rare after tile 0
      float mn = fmaxf(m, pm);
      alpha = expf(m - mn);  // m=-inf -> 0
      m = mn;
#pragma unroll
      for (int reg = 0; reg < 16; ++reg) {
        int qr = (reg & 3) + 8 * (reg >> 2) + 4 * hi;
        float av = __shfl(alpha, qr);
        Oa[0][reg] *= av;
        Oa[1][reg] *= av;
        Oa[2][reg] *= av;
        Oa[3][reg] *= av;
      }
    }
    unsigned int pkhh[4][2], pkll[4][2];
    float ls = 0.0f;
#pragma unroll
    for (int t4 = 0; t4 < 4; ++t4)
#pragma unroll
      for (int c2 = 0; c2 < 2; ++c2) {
        float pa = expf(s[4 * t4 + 2 * c2] - m);
        float pb = expf(s[4 * t4 + 2 * c2 + 1] - m);
        ls += pa + pb;
        _Float16 pah = (_Float16)pa, pbh = (_Float16)pb;
        pkhh[t4][c2] = pk2(pah, pbh);
        pkll[t4][c2] = pk2((_Float16)(pa - (float)pah), (_Float16)(pb - (float)pbh));
      }
    ls += __shfl_xor(ls, 32);
    lsum = lsum * alpha + ls;
    // ---- build PV A-frags: exchange halves across lane^32 ----
    f16x8 paH[2], paL[2];
#pragma unroll
    for (int hf = 0; hf < 2; ++hf) {
      unsigned int curh0 = hi ? pkhh[2 * hf + 1][0] : pkhh[2 * hf][0];
      unsigned int curh1 = hi ? pkhh[2 * hf + 1][1] : pkhh[2 * hf][1];
      unsigned int othh0 = hi ? pkhh[2 * hf][0] : pkhh[2 * hf + 1][0];
      unsigned int othh1 = hi ? pkhh[2 * hf][1] : pkhh[2 * hf + 1][1];
      unsigned int xh0 = (unsigned int)__shfl_xor((int)othh0, 32);
      unsigned int xh1 = (unsigned int)__shfl_xor((int)othh1, 32);
      uint4 uh;
      uh.x = hi ? xh0 : curh0;
      uh.y = hi ? xh1 : curh1;
      uh.z = hi ? curh0 : xh0;
      uh.w = hi ? curh1 : xh1;
      paH[hf] = __builtin_bit_cast(f16x8, uh);
      unsigned int curl0 = hi ? pkll[2 * hf + 1][0] : pkll[2 * hf][0];
      unsigned int curl1 = hi ? pkll[2 * hf + 1][1] : pkll[2 * hf][1];
      unsigned int othl0 = hi ? pkll[2 * hf][0] : pkll[2 * hf + 1][0];
      unsigned int othl1 = hi ? pkll[2 * hf][1] : pkll[2 * hf + 1][1];
      unsigned int xl0 = (unsigned int)__shfl_xor((int)othl0, 32);
      unsigned int xl1 = (unsigned int)__shfl_xor((int)othl1, 32);
      uint4 ul;
      ul.x = hi ? xl0 : curl0;
      ul.y = hi ? xl1 : curl1;
      ul.z = hi ? curl0 : xl0;
      ul.w = hi ? curl1 : xl1;
      paL[hf] = __builtin_bit_cast(f16x8, ul);
    }
    // ---- PV: O += P @ V (3-term split) ----
#pragma unroll
    for (int df = 0; df < 4; ++df) {
#pragma unroll
      for (int hf = 0; hf < 2; ++hf) {
        f16x8 vh = *(const f16x8*)&VhS[bf][(df * 32 + rl) * 40 + hf * 16 + hi8];
        f16x8 vl = *(const f16x8*)&VlS[bf][(df * 32 + rl) * 40 + hf * 16 + hi8];
        Oa[df] = __builtin_amdgcn_mfma_f32_32x32x16_f16(paH[hf], vh, Oa[df], 0, 0, 0);
        Oa[df] = __builtin_amdgcn_mfma_f32_32x32x16_f16(paH[hf], vl, Oa[df], 0, 0, 0);
        Oa[df] = __builtin_amdgcn_mfma_f32_32x32x16_f16(paL[hf], vh, Oa[df], 0, 0, 0);
      }
    }
  }
  // ---- epilogue: divide by l, store in-place into our own q rows ----
  float linv = 1.0f / lsum;
  float* obase = qb + (rowbase + qt * 128 + wave * 32) * 2048 + hcol;
#pragma unroll
  for (int reg = 0; reg < 16; ++reg) {
    int qr = (reg & 3) + 8 * (reg >> 2) + 4 * hi;
    float lv = __shfl(linv, qr);
    float* orow = obase + (size_t)qr * 2048;
    orow[0 * 32 + rl] = Oa[0][reg] * lv;
    orow[1 * 32 + rl] = Oa[1][reg] * lv;
    orow[2 * 32 + rl] = Oa[2][reg] * lv;
    orow[3 * 32 + rl] = Oa[3][reg] * lv;
  }
}

// ---------------- topk(0.55)+int8 quantize per row (exact tie handling) ----
__global__ __launch_bounds__(256) void k_topk(const float* __restrict__ ain,
                                              unsigned short* __restrict__ oq,
                                              float* __restrict__ so) {
  const int row = blockIdx.x, tid = threadIdx.x;
  const float* xr = ain + (size_t)row * 2048;
  __shared__ unsigned int bits[2048];
  __shared__ unsigned int hist[256];
  __shared__ unsigned int scn[256];
  __shared__ unsigned int stat[3];  // prefix, rk, maxbits
#pragma unroll
  for (int j = 0; j < 8; ++j) {
    int i = tid * 8 + j;
    bits[i] = __float_as_uint(xr[i]) & 0x7fffffffu;
  }
  unsigned int mx = 0;
#pragma unroll
  for (int j = 0; j < 8; ++j) mx = max(mx, bits[tid * 8 + j]);
  scn[tid] = mx;
  __syncthreads();
  for (int off = 128; off; off >>= 1) {
    if (tid < off) scn[tid] = max(scn[tid], scn[tid + off]);
    __syncthreads();
  }
  if (tid == 0) { stat[0] = 0u; stat[1] = 1126u; stat[2] = scn[0]; }
  for (int p = 0; p < 4; ++p) {
    const int shift = 24 - 8 * p;
    hist[tid] = 0u;
    __syncthreads();
    unsigned int pref = stat[0];
    unsigned int rk0 = stat[1];
#pragma unroll
    for (int j = 0; j < 8; ++j) {
      unsigned int u = bits[tid * 8 + j];
      bool match = (p == 0) || ((u >> (shift + 8)) == pref);
      if (match) atomicAdd(&hist[(u >> shift) & 255u], 1u);
    }
    __syncthreads();
    scn[tid] = hist[tid];
    __syncthreads();
    for (int off = 1; off < 256; off <<= 1) {
      unsigned int v = (tid + off < 256) ? scn[tid + off] : 0u;
      __syncthreads();
      scn[tid] += v;
      __syncthreads();
    }
    unsigned int nxt = (tid == 255) ? 0u : scn[tid + 1];
    if (scn[tid] >= rk0 && nxt < rk0) {
      stat[0] = (pref << 8) | (unsigned int)tid;
      stat[1] = rk0 - nxt;
    }
    __syncthreads();
  }
  const unsigned int T = stat[0];
  const unsigned int rkeep = stat[1];
  const float rowmax = __uint_as_float(stat[2]);
  const float s = 127.0f / fmaxf(rowmax, 1e-5f);
  unsigned int cnt = 0;
#pragma unroll
  for (int j = 0; j < 8; ++j) cnt += (bits[tid * 8 + j] == T) ? 1u : 0u;
  scn[tid] = cnt;
  __syncthreads();
  for (int off = 1; off < 256; off <<= 1) {
    unsigned int v = (tid >= off) ? scn[tid - off] : 0u;
    __syncthreads();
    scn[tid] += v;
    __syncthreads();
  }
  unsigned int eqr = scn[tid] - cnt;
#pragma unroll
  for (int j = 0; j < 8; ++j) {
    int i = tid * 8 + j;
    unsigned int u = bits[i];
    bool keep = u > T;
    if (u == T) { keep = (eqr < rkeep); eqr++; }
    float q = 0.0f;
    if (keep) {
      q = rintf(xr[i] * s);
      q = fminf(fmaxf(q, -128.0f), 127.0f);
    }
    oq[(size_t)row * 2048 + i] = f2bf(q);
  }
  if (tid == 0) so[row] = s;
}

// ---------------------------------------------------------------------------
extern "C" void kernel_launch(void* const* d_in, const int* in_sizes, int n_in,
                              void* d_out, int out_size, void* d_ws,
                              size_t ws_size, hipStream_t stream) {
  const float* x = (const float*)d_in[0];
  const float* wq = (const float*)d_in[1];
  const float* wk = (const float*)d_in[2];
  const float* wv = (const float*)d_in[3];
  const float* wo = (const float*)d_in[4];
  float* out = (float*)d_out;

  char* ws = (char*)d_ws;
  size_t off = 0;
  auto alloc = [&](size_t bytes) -> void* {
    void* p = ws + off;
    off += (bytes + 255) & ~(size_t)255;
    return p;
  };
  unsigned short* wt = (unsigned short*)alloc(4ull * 2048 * 2048 * 2);  // 33.5MB
  unsigned short* xq = (unsigned short*)alloc(4096ull * 2048 * 2);      // 16.8MB
  float* qb = (float*)alloc(4096ull * 2048 * 4);                        // 33.5MB
  float* kb = (float*)alloc(4096ull * 2048 * 4);
  float* vb = (float*)alloc(4096ull * 2048 * 4);
  _Float16* kl = (_Float16*)alloc(32ull * 2048 * 128 * 2);   // 16.8MB
  _Float16* vth = (_Float16*)alloc(32ull * 128 * 2048 * 2);  // 16.8MB
  _Float16* vtl = (_Float16*)alloc(32ull * 128 * 2048 * 2);  // 16.8MB
  float* ct = (float*)alloc(2048ull * 64 * 4);
  float* st = (float*)alloc(2048ull * 64 * 4);
  float* sx = (float*)alloc(4096 * 4);
  float* so = (float*)alloc(4096 * 4);
  float* wsc = (float*)alloc(4 * 4);
  double* prt = (double*)alloc(4096 * 8);
  _Float16* kh = (_Float16*)xq;              // overlay: xq dead after gemm3
  unsigned short* oq = (unsigned short*)vb;  // overlay: vb dead after vtrans

  k_costab<<<512, 256, 0, stream>>>(ct, st);
  k_wsum<<<4096, 256, 0, stream>>>(wq, wk, wv, wo, prt);
  k_wscale<<<4, 256, 0, stream>>>(prt, wsc);
  k_wquant<<<dim3(1024, 4), 256, 0, stream>>>(wq, wk, wv, wo, wsc, wt);
  k_xquant<<<4096, 256, 0, stream>>>(x, xq, sx);

  k_gemm3<<<dim3(48, 32), 256, 0, stream>>>(xq, wt, qb, kb, vb, sx, wsc);
  k_vtrans<<<dim3(32, 32), 256, 0, stream>>>(vb, vth, vtl);
  k_rope<<<dim3(16384, 2), 256, 0, stream>>>(qb, kb, kh, kl, ct, st);
  k_attn<<<512, 256, 0, stream>>>(qb, kh, kl, vth, vtl);  // O -> qb in-place
  k_topk<<<4096, 256, 0, stream>>>(qb, oq, so);
  k_gemm<<<dim3(16, 32), 256, 0, stream>>>(oq, wt + 3ull * 4194304, out, so,
                                           wsc + 3);
}